// Round 1
// baseline (58.795 us; speedup 1.0000x reference)
//
#include <hip/hip_runtime.h>

#define BATCH 16
#define CH 256
#define HW (128 * 128)   // 16384 elements per channel
#define KSEL 16

// ---- Kernel 1: per-(b,c) mean over H*W ----------------------------------
__global__ __launch_bounds__(256) void mean_kernel(const float* __restrict__ x,
                                                   float* __restrict__ w) {
    const int bc = blockIdx.x;                       // 0 .. BATCH*CH-1
    const int t  = threadIdx.x;                      // 0 .. 255
    const float4* p = reinterpret_cast<const float4*>(x + (size_t)bc * HW);

    float s = 0.0f;
    #pragma unroll
    for (int i = 0; i < HW / 4 / 256; ++i) {         // 16 float4 per thread
        float4 v = p[t + i * 256];
        s += (v.x + v.y) + (v.z + v.w);
    }
    // wave (64-lane) shuffle reduce
    #pragma unroll
    for (int off = 32; off > 0; off >>= 1)
        s += __shfl_down(s, off, 64);

    __shared__ float partial[4];
    const int wave = t >> 6;
    const int lane = t & 63;
    if (lane == 0) partial[wave] = s;
    __syncthreads();
    if (t == 0) {
        float tot = (partial[0] + partial[1]) + (partial[2] + partial[3]);
        w[bc] = tot * (1.0f / (float)HW);
    }
}

// ---- Kernel 2: per-batch bottom-K ranks (stable ascending argsort) ------
__global__ __launch_bounds__(256) void rank_kernel(const float* __restrict__ w,
                                                   int* __restrict__ idx) {
    const int b = blockIdx.x;                        // 0 .. BATCH-1
    const int c = threadIdx.x;                       // 0 .. CH-1
    __shared__ float sw[CH];
    const float mine = w[b * CH + c];
    sw[c] = mine;
    __syncthreads();

    int rank = 0;
    #pragma unroll 8
    for (int j = 0; j < CH; ++j) {
        float v = sw[j];
        rank += (v < mine) || (v == mine && j < c);  // stable tie-break
    }
    if (rank < KSEL) idx[b * KSEL + rank] = c;
}

// ---- Kernel 3: gather selected channels ---------------------------------
__global__ __launch_bounds__(256) void gather_kernel(const float* __restrict__ x,
                                                     const int* __restrict__ idx,
                                                     float* __restrict__ out) {
    const int bk = blockIdx.x;                       // 0 .. BATCH*KSEL-1
    const int b  = bk / KSEL;
    const int c  = idx[bk];
    const int t  = threadIdx.x;

    const float4* src = reinterpret_cast<const float4*>(x + ((size_t)b * CH + c) * HW);
    float4* dst       = reinterpret_cast<float4*>(out + (size_t)bk * HW);

    #pragma unroll
    for (int i = 0; i < HW / 4 / 256; ++i)
        dst[t + i * 256] = src[t + i * 256];
}

extern "C" void kernel_launch(void* const* d_in, const int* in_sizes, int n_in,
                              void* d_out, int out_size, void* d_ws, size_t ws_size,
                              hipStream_t stream) {
    const float* x = (const float*)d_in[0];
    float* out = (float*)d_out;

    float* w  = (float*)d_ws;                                   // BATCH*CH floats
    int*   id = (int*)((char*)d_ws + BATCH * CH * sizeof(float)); // BATCH*KSEL ints

    mean_kernel<<<BATCH * CH, 256, 0, stream>>>(x, w);
    rank_kernel<<<BATCH, 256, 0, stream>>>(w, id);
    gather_kernel<<<BATCH * KSEL, 256, 0, stream>>>(x, id, out);
}

// Round 2
// 57.067 us; speedup vs baseline: 1.0303x; 1.0303x over previous
//
#include <hip/hip_runtime.h>

#define BATCH 16
#define CH 256
#define HW (128 * 128)   // 16384 elements per channel
#define KSEL 16

// ---- Kernel 1: per-(b,c) mean over H*W ----------------------------------
__global__ __launch_bounds__(256) void mean_kernel(const float* __restrict__ x,
                                                   float* __restrict__ w) {
    const int bc = blockIdx.x;                       // 0 .. BATCH*CH-1
    const int t  = threadIdx.x;                      // 0 .. 255
    const float4* p = reinterpret_cast<const float4*>(x + (size_t)bc * HW);

    float s = 0.0f;
    #pragma unroll
    for (int i = 0; i < HW / 4 / 256; ++i) {         // 16 float4 per thread
        float4 v = p[t + i * 256];
        s += (v.x + v.y) + (v.z + v.w);
    }
    // wave (64-lane) shuffle reduce
    #pragma unroll
    for (int off = 32; off > 0; off >>= 1)
        s += __shfl_down(s, off, 64);

    __shared__ float partial[4];
    const int wave = t >> 6;
    const int lane = t & 63;
    if (lane == 0) partial[wave] = s;
    __syncthreads();
    if (t == 0) {
        float tot = (partial[0] + partial[1]) + (partial[2] + partial[3]);
        w[bc] = tot * (1.0f / (float)HW);
    }
}

// ---- Kernel 2 (fused): per-block rank recompute + channel gather --------
// Block bk = b*KSEL + k. All 256 threads load w[b][:] into LDS, each thread c
// computes the stable-ascending rank of channel c; the thread whose rank == k
// publishes its channel. Then the whole block copies that 64 KiB channel.
__global__ __launch_bounds__(256) void rank_gather_kernel(const float* __restrict__ x,
                                                          const float* __restrict__ w,
                                                          float* __restrict__ out) {
    const int bk = blockIdx.x;                       // 0 .. BATCH*KSEL-1
    const int b  = bk >> 4;
    const int k  = bk & (KSEL - 1);
    const int t  = threadIdx.x;                      // 0 .. 255 (== channel id)

    __shared__ float sw[CH];
    __shared__ int   sel;
    sw[t] = w[b * CH + t];
    __syncthreads();

    const float mine = sw[t];
    int rank = 0;
    #pragma unroll 8
    for (int j = 0; j < CH; ++j) {
        float v = sw[j];
        rank += (v < mine) || (v == mine && j < t);  // stable tie-break
    }
    if (rank == k) sel = t;                          // exactly one thread matches
    __syncthreads();
    const int c = sel;

    const float4* src = reinterpret_cast<const float4*>(x + ((size_t)b * CH + c) * HW);
    float4* dst       = reinterpret_cast<float4*>(out + (size_t)bk * HW);

    #pragma unroll
    for (int i = 0; i < HW / 4 / 256; ++i)
        dst[t + i * 256] = src[t + i * 256];
}

extern "C" void kernel_launch(void* const* d_in, const int* in_sizes, int n_in,
                              void* d_out, int out_size, void* d_ws, size_t ws_size,
                              hipStream_t stream) {
    const float* x = (const float*)d_in[0];
    float* out = (float*)d_out;

    float* w = (float*)d_ws;                         // BATCH*CH floats

    mean_kernel<<<BATCH * CH, 256, 0, stream>>>(x, w);
    rank_gather_kernel<<<BATCH * KSEL, 256, 0, stream>>>(x, w, out);
}